// Round 1
// 190.403 us; speedup vs baseline: 1.0156x; 1.0156x over previous
//
#include <hip/hip_runtime.h>
#include <math.h>

#define NATOMS 128
#define NALIGN 64
#define FPB    8      // frames per block: 32 threads per frame (4 atoms/thread)
#define TPB    256

// Jacobi rotation on symmetric 3x3 for pair (p,q); third index r.
#define JACOBI_ROT(app, aqq, apq, arp, arq, pcol, qcol)                 \
  {                                                                     \
    float _apq = (apq);                                                 \
    if (fabsf(_apq) > 1e-20f) {                                         \
      float _tau = ((aqq) - (app)) / (2.0f * _apq);                     \
      float _t = (_tau >= 0.0f ? 1.0f : -1.0f) /                        \
                 (fabsf(_tau) + sqrtf(1.0f + _tau * _tau));             \
      float _c = rsqrtf(1.0f + _t * _t);                                \
      float _s = _t * _c;                                               \
      (app) -= _t * _apq;                                               \
      (aqq) += _t * _apq;                                               \
      (apq) = 0.0f;                                                     \
      float _rp = (arp), _rq = (arq);                                   \
      (arp) = _c * _rp - _s * _rq;                                      \
      (arq) = _s * _rp + _c * _rq;                                      \
      _Pragma("unroll")                                                 \
      for (int _r = 0; _r < 3; _r++) {                                  \
        float _vp = v[3 * _r + (pcol)], _vq = v[3 * _r + (qcol)];       \
        v[3 * _r + (pcol)] = _c * _vp - _s * _vq;                       \
        v[3 * _r + (qcol)] = _s * _vp + _c * _vq;                       \
      }                                                                 \
    }                                                                   \
  }

__global__ __launch_bounds__(TPB) void align_kernel(
    const float* __restrict__ traj,
    const float* __restrict__ ref_pos,
    const int* __restrict__ align_idx,
    float* __restrict__ out,
    int B)
{
    // Inverse ref map: for atom a, (centered ref xyz, weight). Stored at
    // swizzled slot ((a&3)<<5)|(a>>2) so lane r's 4 reads (atoms 4r..4r+3)
    // are stride-16B ds_read_b128 (conflict-free) instead of stride-64B.
    __shared__ float4 s_rmap[NATOMS];
    __shared__ __align__(16) float s_mat[FPB][12];   // prod(9)+xc(3) -> R(9)+xc(3)

    const int t  = threadIdx.x;
    const int f0 = blockIdx.x * FPB;
    const int f  = t >> 5;       // local frame 0..7
    const int r  = t & 31;       // 4-atom chunk within frame
    const int gf = f0 + f;
    const bool valid = (gf < B);

    // ---------- issue the ONE global read of this thread's 4 atoms ----------
    float4 q0, q1, q2;
    if (valid) {
        const float* p = traj + (size_t)gf * (NATOMS * 3) + r * 12;
        q0 = *(const float4*)(p);
        q1 = *(const float4*)(p + 4);
        q2 = *(const float4*)(p + 8);
    } else {
        q0 = q1 = q2 = make_float4(0.f, 0.f, 0.f, 0.f);
    }

    // ---------- Stage 0 (wave 0 only): build centered-ref inverse map ----------
    if (t < NALIGN) {
        // zero all 128 slots first (wave-internal program order makes this
        // safe w.r.t. the fill below: same wave, DS ops retire in order)
        const float4 z4 = make_float4(0.f, 0.f, 0.f, 0.f);
        s_rmap[t]          = z4;
        s_rmap[t + NALIGN] = z4;

        int idx = align_idx[t];
        float rx = ref_pos[idx * 3 + 0];
        float ry = ref_pos[idx * 3 + 1];
        float rz = ref_pos[idx * 3 + 2];
        float sx = rx, sy = ry, sz = rz;
        #pragma unroll
        for (int off = 32; off >= 1; off >>= 1) {
            sx += __shfl_xor(sx, off);
            sy += __shfl_xor(sy, off);
            sz += __shfl_xor(sz, off);
        }
        const float inv = 1.0f / (float)NALIGN;
        int slot = ((idx & 3) << 5) | (idx >> 2);
        s_rmap[slot] = make_float4(rx - sx * inv, ry - sy * inv, rz - sz * inv, 1.0f);
    }
    __syncthreads();

    // ---------- Stage 1: centroid + cross-covariance from registers ----------
    // atoms: a0=(q0.x,q0.y,q0.z) a1=(q0.w,q1.x,q1.y)
    //        a2=(q1.z,q1.w,q2.x) a3=(q2.y,q2.z,q2.w)
    float xx[4] = { q0.x, q0.w, q1.z, q2.y };
    float yy[4] = { q0.y, q1.x, q1.w, q2.z };
    float zz[4] = { q0.z, q1.y, q2.x, q2.w };

    {
        float sx = 0.f, sy = 0.f, sz = 0.f;
        float c[9] = {0.f,0.f,0.f,0.f,0.f,0.f,0.f,0.f,0.f};
        #pragma unroll
        for (int j = 0; j < 4; j++) {
            float4 rm = s_rmap[(j << 5) | r];
            // centroid over aligned subset (w=1 aligned, 0 otherwise)
            sx += rm.w * xx[j]; sy += rm.w * yy[j]; sz += rm.w * zz[j];
            // cov = sum x (x-outer-r); centering of x unnecessary: sum(r)=0
            c[0] += xx[j]*rm.x; c[1] += xx[j]*rm.y; c[2] += xx[j]*rm.z;
            c[3] += yy[j]*rm.x; c[4] += yy[j]*rm.y; c[5] += yy[j]*rm.z;
            c[6] += zz[j]*rm.x; c[7] += zz[j]*rm.y; c[8] += zz[j]*rm.z;
        }
        // reduce over the frame's 32 lanes (xor <=16 stays in the group)
        #pragma unroll
        for (int off = 16; off >= 1; off >>= 1) {
            sx += __shfl_xor(sx, off);
            sy += __shfl_xor(sy, off);
            sz += __shfl_xor(sz, off);
            #pragma unroll
            for (int jj = 0; jj < 9; jj++) c[jj] += __shfl_xor(c[jj], off);
        }
        if (r == 0 && valid) {
            #pragma unroll
            for (int jj = 0; jj < 9; jj++) s_mat[f][jj] = c[jj];
            const float inv = 1.0f / (float)NALIGN;
            s_mat[f][9]  = sx * inv;
            s_mat[f][10] = sy * inv;
            s_mat[f][11] = sz * inv;
        }
    }
    __syncthreads();

    // ---------- Stage 2: 3x3 SVD -> rotation (one lane per frame) ----------
    if (t < FPB && (f0 + t) < B) {
        float m[9];
        #pragma unroll
        for (int j = 0; j < 9; j++) m[j] = s_mat[t][j];

        // A = M^T M (symmetric)
        float a00 = m[0]*m[0] + m[3]*m[3] + m[6]*m[6];
        float a01 = m[0]*m[1] + m[3]*m[4] + m[6]*m[7];
        float a02 = m[0]*m[2] + m[3]*m[5] + m[6]*m[8];
        float a11 = m[1]*m[1] + m[4]*m[4] + m[7]*m[7];
        float a12 = m[1]*m[2] + m[4]*m[5] + m[7]*m[8];
        float a22 = m[2]*m[2] + m[5]*m[5] + m[8]*m[8];

        float v[9] = {1.f,0.f,0.f, 0.f,1.f,0.f, 0.f,0.f,1.f};
        #pragma unroll
        for (int sweep = 0; sweep < 5; sweep++) {
            JACOBI_ROT(a00, a11, a01, a02, a12, 0, 1);
            JACOBI_ROT(a00, a22, a02, a01, a12, 0, 2);
            JACOBI_ROT(a11, a22, a12, a01, a02, 1, 2);
        }

        // sort eigenvalues descending, permuting V columns
        float dd[3] = {a00, a11, a22};
        #pragma unroll
        for (int pass = 0; pass < 3; pass++) {
            int ii = (pass == 0) ? 0 : (pass == 1) ? 0 : 1;
            int jj = (pass == 0) ? 1 : 2;
            if (dd[ii] < dd[jj]) {
                float tmp = dd[ii]; dd[ii] = dd[jj]; dd[jj] = tmp;
                #pragma unroll
                for (int rr = 0; rr < 3; rr++) {
                    float tv = v[3*rr+ii]; v[3*rr+ii] = v[3*rr+jj]; v[3*rr+jj] = tv;
                }
            }
        }

        float v0x = v[0], v0y = v[3], v0z = v[6];
        float v1x = v[1], v1y = v[4], v1z = v[7];
        float v2x = v[2], v2y = v[5], v2z = v[8];

        // u1 = normalize(M v0)
        float u1x = m[0]*v0x + m[1]*v0y + m[2]*v0z;
        float u1y = m[3]*v0x + m[4]*v0y + m[5]*v0z;
        float u1z = m[6]*v0x + m[7]*v0y + m[8]*v0z;
        float n1 = rsqrtf(fmaxf(u1x*u1x + u1y*u1y + u1z*u1z, 1e-30f));
        u1x *= n1; u1y *= n1; u1z *= n1;

        // u2 = normalize(M v1 - (u1 . M v1) u1)
        float u2x = m[0]*v1x + m[1]*v1y + m[2]*v1z;
        float u2y = m[3]*v1x + m[4]*v1y + m[5]*v1z;
        float u2z = m[6]*v1x + m[7]*v1y + m[8]*v1z;
        float d12 = u1x*u2x + u1y*u2y + u1z*u2z;
        u2x -= d12 * u1x; u2y -= d12 * u1y; u2z -= d12 * u1z;
        float n2 = rsqrtf(fmaxf(u2x*u2x + u2y*u2y + u2z*u2z, 1e-30f));
        u2x *= n2; u2y *= n2; u2z *= n2;

        // u3 = (u1 x u2) * sign(det V)
        float u3x = u1y*u2z - u1z*u2y;
        float u3y = u1z*u2x - u1x*u2z;
        float u3z = u1x*u2y - u1y*u2x;
        float cx = v1y*v2z - v1z*v2y;
        float cy = v1z*v2x - v1x*v2z;
        float cz = v1x*v2y - v1y*v2x;
        float detv = v0x*cx + v0y*cy + v0z*cz;
        float sg = (detv >= 0.f) ? 1.f : -1.f;
        u3x *= sg; u3y *= sg; u3z *= sg;

        // R[a][b] = u1[a]*v0[b] + u2[a]*v1[b] + u3[a]*v2[b]  (row-major)
        s_mat[t][0] = u1x*v0x + u2x*v1x + u3x*v2x;
        s_mat[t][1] = u1x*v0y + u2x*v1y + u3x*v2y;
        s_mat[t][2] = u1x*v0z + u2x*v1z + u3x*v2z;
        s_mat[t][3] = u1y*v0x + u2y*v1x + u3y*v2x;
        s_mat[t][4] = u1y*v0y + u2y*v1y + u3y*v2y;
        s_mat[t][5] = u1y*v0z + u2y*v1z + u3y*v2z;
        s_mat[t][6] = u1z*v0x + u2z*v1x + u3z*v2x;
        s_mat[t][7] = u1z*v0y + u2z*v1y + u3z*v2y;
        s_mat[t][8] = u1z*v0z + u2z*v1z + u3z*v2z;
        // s_mat[t][9..11] keeps xc
    }
    __syncthreads();

    // ---------- Stage 3: rotate the register-resident atoms, store ----------
    if (valid) {
        float4 Ra = *(const float4*)&s_mat[f][0];   // R0 R1 R2 R3  (broadcast)
        float4 Rb = *(const float4*)&s_mat[f][4];   // R4 R5 R6 R7
        float4 Rc = *(const float4*)&s_mat[f][8];   // R8 xcx xcy xcz
        float R0 = Ra.x, R1 = Ra.y, R2 = Ra.z, R3 = Ra.w;
        float R4 = Rb.x, R5 = Rb.y, R6 = Rb.z, R7 = Rb.w;
        float R8 = Rc.x, xcx = Rc.y, xcy = Rc.z, xcz = Rc.w;

        float ox[4], oy[4], oz[4];
        #pragma unroll
        for (int j = 0; j < 4; j++) {
            float dx = xx[j] - xcx, dy = yy[j] - xcy, dz = zz[j] - xcz;
            ox[j] = dx*R0 + dy*R3 + dz*R6;
            oy[j] = dx*R1 + dy*R4 + dz*R7;
            oz[j] = dx*R2 + dy*R5 + dz*R8;
        }

        float* po = out + (size_t)gf * (NATOMS * 3) + r * 12;
        *(float4*)(po)     = make_float4(ox[0], oy[0], oz[0], ox[1]);
        *(float4*)(po + 4) = make_float4(oy[1], oz[1], ox[2], oy[2]);
        *(float4*)(po + 8) = make_float4(oz[2], ox[3], oy[3], oz[3]);
    }
}

extern "C" void kernel_launch(void* const* d_in, const int* in_sizes, int n_in,
                              void* d_out, int out_size, void* d_ws, size_t ws_size,
                              hipStream_t stream) {
    const float* traj      = (const float*)d_in[0];
    const float* ref_pos   = (const float*)d_in[1];
    const int*   align_idx = (const int*)d_in[2];
    float*       out       = (float*)d_out;

    int B = in_sizes[0] / (NATOMS * 3);
    int grid = (B + FPB - 1) / FPB;
    align_kernel<<<grid, TPB, 0, stream>>>(traj, ref_pos, align_idx, out, B);
}